// Round 2
// baseline (502.834 us; speedup 1.0000x reference)
//
#include <hip/hip_runtime.h>

typedef unsigned short u16;
typedef _Float16 f16;
typedef __attribute__((ext_vector_type(8))) f16 f16x8;
typedef __attribute__((ext_vector_type(4))) float f32x4;
typedef __attribute__((ext_vector_type(4))) u16 u16x4;
typedef __attribute__((ext_vector_type(8))) u16 u16x8;

__device__ __forceinline__ u16 f2h(float x){
  f16 h = (f16)x;
  return __builtin_bit_cast(u16, h);
}

__device__ __forceinline__ void stage16(const void* g, void* l){
  __builtin_amdgcn_global_load_lds(
      (const __attribute__((address_space(1))) unsigned*)g,
      (__attribute__((address_space(3))) unsigned*)l, 16, 0, 0);
}

// ---------------- converts ----------------
// fp32 [M][K] -> f16 same layout (A operands), coalesced
__global__ __launch_bounds__(256) void convert_x(const float* __restrict__ in,
                                                 u16* __restrict__ out, int n4){
  int i = blockIdx.x * 256 + threadIdx.x;
  if (i >= n4) return;
  f32x4 v = ((const f32x4*)in)[i];
  u16x4 h;
  #pragma unroll
  for (int j = 0; j < 4; j++) h[j] = f2h(v[j]);
  ((u16x4*)out)[i] = h;
}

// W fp32 [1024][1024] -> W^T f16 [n][k], LDS-tiled 64x64 transpose
__global__ __launch_bounds__(256) void transpose_w(const float* __restrict__ W,
                                                   u16* __restrict__ wt){
  __shared__ float tile[64][68];                // 68 floats: rows 272B, 16B-aligned
  const int tid = threadIdx.x;
  const int k0 = blockIdx.y * 64, n0 = blockIdx.x * 64;
  #pragma unroll
  for (int g = 0; g < 4; g++){
    int flat4 = g * 256 + tid;
    int row = flat4 >> 4, c4 = flat4 & 15;
    f32x4 v = *(const f32x4*)&W[(size_t)(k0 + row) * 1024 + n0 + c4 * 4];
    *(f32x4*)&tile[row][c4 * 4] = v;
  }
  __syncthreads();
  const int n = tid >> 2, kc = (tid & 3) * 16;
  u16x8 o0, o1;
  #pragma unroll
  for (int j = 0; j < 8; j++){
    o0[j] = f2h(tile[kc + j][n]);
    o1[j] = f2h(tile[kc + 8 + j][n]);
  }
  u16* dst = &wt[(size_t)(n0 + n) * 1024 + k0 + kc];
  *(u16x8*)dst = o0;
  *(u16x8*)(dst + 8) = o1;
}

// ---------------- GEMM: C[M][N] = A[M][K] * Bt[N][K], f16 MFMA ----------------
// MODE 0: fp32 out[m*N+n] + bias[n]
// MODE 1: q/k: write f16 at [b][h][s][64]  (m=b*2048+s, n=h*64+d), + bias[n]
// MODE 2: v^T: write f16 at [b][h][d][s]   (m=channel, n=token), + bias[m]
template<int MODE>
__global__ __launch_bounds__(256, 2) void gemm_bt(
    const u16* __restrict__ A, const u16* __restrict__ B,
    const float* __restrict__ bias,
    float* __restrict__ outF, u16* __restrict__ outH,
    int N, int K)
{
  __shared__ u16 sA[128 * 32];
  __shared__ u16 sB[128 * 32];
  const int tid = threadIdx.x;
  const int wid = tid >> 6, lane = tid & 63;
  const int lm = lane & 15, lg = lane >> 4;
  const int bm = blockIdx.y * 128, bn = blockIdx.x * 128;
  const int wrow = (wid >> 1) * 64, wcol = (wid & 1) * 64;
  const int srow = tid >> 2;
  const int skc  = (tid & 3) * 8;

  f32x4 acc[4][4] = {};

  for (int kt = 0; kt < K; kt += 32){
    {
      char* dA = (char*)sA + wid * 1024;
      char* dB = (char*)sB + wid * 1024;
      stage16(A + (size_t)(bm +      srow) * K + kt + skc, dA);
      stage16(A + (size_t)(bm + 64 + srow) * K + kt + skc, dA + 4096);
      stage16(B + (size_t)(bn +      srow) * K + kt + skc, dB);
      stage16(B + (size_t)(bn + 64 + srow) * K + kt + skc, dB + 4096);
    }
    __syncthreads();
    f16x8 af[4], bf[4];
    #pragma unroll
    for (int mf = 0; mf < 4; mf++)
      af[mf] = *(const f16x8*)&sA[(wrow + mf * 16 + lm) * 32 + lg * 8];
    #pragma unroll
    for (int nf = 0; nf < 4; nf++)
      bf[nf] = *(const f16x8*)&sB[(wcol + nf * 16 + lm) * 32 + lg * 8];
    #pragma unroll
    for (int mf = 0; mf < 4; mf++)
      #pragma unroll
      for (int nf = 0; nf < 4; nf++)
        acc[mf][nf] = __builtin_amdgcn_mfma_f32_16x16x32_f16(af[mf], bf[nf], acc[mf][nf], 0, 0, 0);
    __syncthreads();
  }

  #pragma unroll
  for (int mf = 0; mf < 4; mf++)
    #pragma unroll
    for (int nf = 0; nf < 4; nf++){
      const int n  = bn + wcol + nf * 16 + lm;
      const int mb = bm + wrow + mf * 16 + lg * 4;
      #pragma unroll
      for (int r = 0; r < 4; r++){
        const int m = mb + r;
        float v = acc[mf][nf][r] + ((MODE == 2) ? bias[m] : bias[n]);
        if constexpr (MODE == 0){
          outF[(size_t)m * N + n] = v;
        } else if constexpr (MODE == 1){
          const size_t idx = (((size_t)((m >> 11) * 16 + (n >> 6))) * 2048 + (m & 2047)) * 64 + (n & 63);
          outH[idx] = f2h(v);
        } else {
          const size_t idx = (((size_t)((n >> 11) * 16 + (m >> 6))) * 64 + (m & 63)) * 2048 + (n & 2047);
          outH[idx] = f2h(v);
        }
      }
    }
}

// ---------------- fused attention ----------------
// per wave: 32 q-rows of one (b,h). Pass A: l = sum(exp(s)).
// Pass B: identical scores, attn write (fp32), PV via per-wave LDS transpose.
__global__ __launch_bounds__(256, 2) void attn_fused(
    const u16* __restrict__ qh_, const u16* __restrict__ kh_,
    const u16* __restrict__ vt_,
    float* __restrict__ attn_out, u16* __restrict__ ctx)
{
  constexpr int S = 2048;
  __shared__ u16 te[4][32][40];                 // pad 40 -> 80B rows, 16B aligned
  const int tid = threadIdx.x, wid = tid >> 6, lane = tid & 63;
  const int lm = lane & 15, lg = lane >> 4;
  // bijective XCD swizzle: each XCD owns 4 consecutive bh values entirely
  const int wg = blockIdx.y * 16 + blockIdx.x;  // 512 wgs
  const int xcd = wg & 7, li = wg >> 3;
  const int bh = (xcd << 2) + (li >> 4);        // 0..31
  const int q0 = (li & 15) * 128 + wid * 32;
  const size_t base = (size_t)bh * S * 64;
  const u16* Qh = qh_ + base;
  const u16* Kh = kh_ + base;
  const u16* Vt = vt_ + base;                   // [64][S]
  float* Aout = attn_out + (size_t)bh * S * S;

  f16x8 aq[2][2];                               // [mfrag][kstep]
  #pragma unroll
  for (int mf = 0; mf < 2; mf++)
    #pragma unroll
    for (int ks = 0; ks < 2; ks++)
      aq[mf][ks] = *(const f16x8*)(Qh + (size_t)(q0 + mf * 16 + lm) * 64 + ks * 32 + lg * 8);

  const float SCL = 0.125f;                     // 1/sqrt(64)
  float lsum[2][4] = {};
  for (int nt = 0; nt < 128; nt++){             // pass A
    f32x4 c[2] = {};
    #pragma unroll
    for (int ks = 0; ks < 2; ks++){
      f16x8 kb = *(const f16x8*)(Kh + (size_t)(nt * 16 + lm) * 64 + ks * 32 + lg * 8);
      c[0] = __builtin_amdgcn_mfma_f32_16x16x32_f16(aq[0][ks], kb, c[0], 0, 0, 0);
      c[1] = __builtin_amdgcn_mfma_f32_16x16x32_f16(aq[1][ks], kb, c[1], 0, 0, 0);
    }
    #pragma unroll
    for (int mf = 0; mf < 2; mf++)
      #pragma unroll
      for (int r = 0; r < 4; r++)
        lsum[mf][r] += __expf(c[mf][r] * SCL);
  }
  #pragma unroll
  for (int m = 1; m < 16; m <<= 1)
    #pragma unroll
    for (int mf = 0; mf < 2; mf++)
      #pragma unroll
      for (int r = 0; r < 4; r++)
        lsum[mf][r] += __shfl_xor(lsum[mf][r], m);
  float inv[2][4];
  #pragma unroll
  for (int mf = 0; mf < 2; mf++)
    #pragma unroll
    for (int r = 0; r < 4; r++)
      inv[mf][r] = 1.0f / lsum[mf][r];

  f32x4 cacc[2][4] = {};
  for (int nt2 = 0; nt2 < 64; nt2++){           // pass B, 32-k chunks
    #pragma unroll
    for (int half = 0; half < 2; half++){
      const int nt = nt2 * 2 + half;
      f32x4 c[2] = {};
      #pragma unroll
      for (int ks = 0; ks < 2; ks++){
        f16x8 kb = *(const f16x8*)(Kh + (size_t)(nt * 16 + lm) * 64 + ks * 32 + lg * 8);
        c[0] = __builtin_amdgcn_mfma_f32_16x16x32_f16(aq[0][ks], kb, c[0], 0, 0, 0);
        c[1] = __builtin_amdgcn_mfma_f32_16x16x32_f16(aq[1][ks], kb, c[1], 0, 0, 0);
      }
      #pragma unroll
      for (int mf = 0; mf < 2; mf++)
        #pragma unroll
        for (int r = 0; r < 4; r++){
          float a = __expf(c[mf][r] * SCL) * inv[mf][r];
          int row = mf * 16 + lg * 4 + r;
          Aout[(size_t)(q0 + row) * S + nt * 16 + lm] = a;
          te[wid][row][half * 16 + lm] = f2h(a);
        }
    }
    f16x8 pa0 = *(const f16x8*)&te[wid][lm][lg * 8];
    f16x8 pa1 = *(const f16x8*)&te[wid][16 + lm][lg * 8];
    #pragma unroll
    for (int nf = 0; nf < 4; nf++){
      f16x8 vb = *(const f16x8*)(Vt + (size_t)(nf * 16 + lm) * S + nt2 * 32 + lg * 8);
      cacc[0][nf] = __builtin_amdgcn_mfma_f32_16x16x32_f16(pa0, vb, cacc[0][nf], 0, 0, 0);
      cacc[1][nf] = __builtin_amdgcn_mfma_f32_16x16x32_f16(pa1, vb, cacc[1][nf], 0, 0, 0);
    }
  }
  const int b = bh >> 4, h = bh & 15;
  #pragma unroll
  for (int mf = 0; mf < 2; mf++)
    #pragma unroll
    for (int nf = 0; nf < 4; nf++)
      #pragma unroll
      for (int r = 0; r < 4; r++){
        int srow2 = q0 + mf * 16 + lg * 4 + r;
        int d = nf * 16 + lm;
        ctx[(size_t)(b * 2048 + srow2) * 1024 + h * 64 + d] = f2h(cacc[mf][nf][r]);
      }
}

// ---------------- host ----------------
extern "C" void kernel_launch(void* const* d_in, const int* in_sizes, int n_in,
                              void* d_out, int out_size, void* d_ws, size_t ws_size,
                              hipStream_t stream) {
  const float* Qi  = (const float*)d_in[0];
  const float* Ki  = (const float*)d_in[1];
  const float* Vi  = (const float*)d_in[2];
  const float* Wq  = (const float*)d_in[3];
  const float* bq  = (const float*)d_in[4];
  const float* Wk  = (const float*)d_in[5];
  const float* bk  = (const float*)d_in[6];
  const float* Wv  = (const float*)d_in[7];
  const float* bv  = (const float*)d_in[8];
  const float* Wfc = (const float*)d_in[9];
  const float* bfc = (const float*)d_in[10];

  char* w = (char*)d_ws;
  const size_t P  = 8388608;    // 8 MB
  const size_t PW = 2097152;    // 2 MB
  u16* xq  = (u16*)(w + 0*P);
  u16* xk  = (u16*)(w + 1*P);
  u16* xv  = (u16*)(w + 2*P);
  u16* qh  = (u16*)(w + 3*P);
  u16* kh  = (u16*)(w + 4*P);
  u16* vt  = (u16*)(w + 5*P);
  u16* ctx = (u16*)(w + 6*P);
  char* w2 = w + 7*P;
  u16* wqt = (u16*)(w2 + 0*PW);
  u16* wkt = (u16*)(w2 + 1*PW);
  u16* wvt = (u16*)(w2 + 2*PW);
  u16* wft = (u16*)(w2 + 3*PW);

  float* outp  = (float*)d_out;
  float* attnp = outp + 4194304;          // out = 2*2048*1024

  convert_x<<<4096, 256, 0, stream>>>(Qi, xq, 1048576);
  convert_x<<<4096, 256, 0, stream>>>(Ki, xk, 1048576);
  convert_x<<<4096, 256, 0, stream>>>(Vi, xv, 1048576);
  transpose_w<<<dim3(16, 16), 256, 0, stream>>>(Wq,  wqt);
  transpose_w<<<dim3(16, 16), 256, 0, stream>>>(Wk,  wkt);
  transpose_w<<<dim3(16, 16), 256, 0, stream>>>(Wv,  wvt);
  transpose_w<<<dim3(16, 16), 256, 0, stream>>>(Wfc, wft);

  // q,k projections: head-major f16 output
  gemm_bt<1><<<dim3(8, 32), 256, 0, stream>>>(xq, wqt, bq, nullptr, qh, 1024, 1024);
  gemm_bt<1><<<dim3(8, 32), 256, 0, stream>>>(xk, wkt, bk, nullptr, kh, 1024, 1024);
  // v projection, transposed output v^T[b][h][d][s]
  gemm_bt<2><<<dim3(32, 8), 256, 0, stream>>>(wvt, xv, bv, nullptr, vt, 4096, 1024);
  // fused scores + softmax + attn-write + PV
  attn_fused<<<dim3(16, 32), 256, 0, stream>>>(qh, kh, vt, attnp, ctx);
  // output projection
  gemm_bt<0><<<dim3(8, 32), 256, 0, stream>>>(ctx, wft, bfc, outp, nullptr, 1024, 1024);
}

// Round 3
// 456.646 us; speedup vs baseline: 1.1011x; 1.1011x over previous
//
#include <hip/hip_runtime.h>

typedef unsigned short u16;
typedef _Float16 f16;
typedef __attribute__((ext_vector_type(8))) f16 f16x8;
typedef __attribute__((ext_vector_type(4))) float f32x4;
typedef __attribute__((ext_vector_type(4))) u16 u16x4;
typedef __attribute__((ext_vector_type(8))) u16 u16x8;

__device__ __forceinline__ u16 f2h(float x){
  f16 h = (f16)x;
  return __builtin_bit_cast(u16, h);
}

__device__ __forceinline__ void stage16(const void* g, void* l){
  __builtin_amdgcn_global_load_lds(
      (const __attribute__((address_space(1))) unsigned*)g,
      (__attribute__((address_space(3))) unsigned*)l, 16, 0, 0);
}

// ---------------- converts ----------------
// 3x fp32 [N] -> f16, one launch. 4096 blocks per tensor.
__global__ __launch_bounds__(256) void convert_x3(
    const float* __restrict__ in0, const float* __restrict__ in1, const float* __restrict__ in2,
    u16* __restrict__ o0, u16* __restrict__ o1, u16* __restrict__ o2){
  const int b = blockIdx.x >> 12;
  const int i = (blockIdx.x & 4095) * 256 + threadIdx.x;
  const float* in = (b == 0) ? in0 : (b == 1) ? in1 : in2;
  u16* out = (b == 0) ? o0 : (b == 1) ? o1 : o2;
  f32x4 v = ((const f32x4*)in)[i];
  u16x4 h;
  #pragma unroll
  for (int j = 0; j < 4; j++) h[j] = f2h(v[j]);
  ((u16x4*)out)[i] = h;
}

// 4x W fp32 [1024][1024] -> W^T f16 [n][k], LDS-tiled, one launch (z selects)
__global__ __launch_bounds__(256) void transpose_w4(
    const float* __restrict__ W0, const float* __restrict__ W1,
    const float* __restrict__ W2, const float* __restrict__ W3,
    u16* __restrict__ t0, u16* __restrict__ t1, u16* __restrict__ t2, u16* __restrict__ t3){
  __shared__ float tile[64][68];
  const int z = blockIdx.z;
  const float* W = (z == 0) ? W0 : (z == 1) ? W1 : (z == 2) ? W2 : W3;
  u16* wt = (z == 0) ? t0 : (z == 1) ? t1 : (z == 2) ? t2 : t3;
  const int tid = threadIdx.x;
  const int k0 = blockIdx.y * 64, n0 = blockIdx.x * 64;
  #pragma unroll
  for (int g = 0; g < 4; g++){
    int flat4 = g * 256 + tid;
    int row = flat4 >> 4, c4 = flat4 & 15;
    f32x4 v = *(const f32x4*)&W[(size_t)(k0 + row) * 1024 + n0 + c4 * 4];
    *(f32x4*)&tile[row][c4 * 4] = v;
  }
  __syncthreads();
  const int n = tid >> 2, kc = (tid & 3) * 16;
  u16x8 o0, o1;
  #pragma unroll
  for (int j = 0; j < 8; j++){
    o0[j] = f2h(tile[kc + j][n]);
    o1[j] = f2h(tile[kc + 8 + j][n]);
  }
  u16* dst = &wt[(size_t)(n0 + n) * 1024 + k0 + kc];
  *(u16x8*)dst = o0;
  *(u16x8*)(dst + 8) = o1;
}

// ---------------- GEMM body: C[M][N] = A[M][K] * Bt[N][K], f16 MFMA ----------------
// MODE 0: fp32 out[m*N+n] + bias[n]
// MODE 1: q/k: f16 at [b][h][s][64]  (m=b*2048+s, n=h*64+d), + bias[n]
// MODE 2: v^T: f16 at [b][h][d][s]   (m=channel, n=token), + bias[m]
template<int MODE>
__device__ __forceinline__ void gemm_body(
    const u16* __restrict__ A, const u16* __restrict__ B,
    const float* __restrict__ bias,
    float* __restrict__ outF, u16* __restrict__ outH,
    int N, int K, int bx, int by)
{
  __shared__ u16 sA[128 * 32];
  __shared__ u16 sB[128 * 32];
  const int tid = threadIdx.x;
  const int wid = tid >> 6, lane = tid & 63;
  const int lm = lane & 15, lg = lane >> 4;
  const int bm = by * 128, bn = bx * 128;
  const int wrow = (wid >> 1) * 64, wcol = (wid & 1) * 64;
  const int srow = tid >> 2;
  const int skc  = (tid & 3) * 8;

  f32x4 acc[4][4] = {};

  for (int kt = 0; kt < K; kt += 32){
    {
      char* dA = (char*)sA + wid * 1024;
      char* dB = (char*)sB + wid * 1024;
      stage16(A + (size_t)(bm +      srow) * K + kt + skc, dA);
      stage16(A + (size_t)(bm + 64 + srow) * K + kt + skc, dA + 4096);
      stage16(B + (size_t)(bn +      srow) * K + kt + skc, dB);
      stage16(B + (size_t)(bn + 64 + srow) * K + kt + skc, dB + 4096);
    }
    __syncthreads();
    f16x8 af[4], bf[4];
    #pragma unroll
    for (int mf = 0; mf < 4; mf++)
      af[mf] = *(const f16x8*)&sA[(wrow + mf * 16 + lm) * 32 + lg * 8];
    #pragma unroll
    for (int nf = 0; nf < 4; nf++)
      bf[nf] = *(const f16x8*)&sB[(wcol + nf * 16 + lm) * 32 + lg * 8];
    #pragma unroll
    for (int mf = 0; mf < 4; mf++)
      #pragma unroll
      for (int nf = 0; nf < 4; nf++)
        acc[mf][nf] = __builtin_amdgcn_mfma_f32_16x16x32_f16(af[mf], bf[nf], acc[mf][nf], 0, 0, 0);
    __syncthreads();
  }

  #pragma unroll
  for (int mf = 0; mf < 4; mf++)
    #pragma unroll
    for (int nf = 0; nf < 4; nf++){
      const int n  = bn + wcol + nf * 16 + lm;
      const int mb = bm + wrow + mf * 16 + lg * 4;
      #pragma unroll
      for (int r = 0; r < 4; r++){
        const int m = mb + r;
        float v = acc[mf][nf][r] + ((MODE == 2) ? bias[m] : bias[n]);
        if constexpr (MODE == 0){
          outF[(size_t)m * N + n] = v;
        } else if constexpr (MODE == 1){
          const size_t idx = (((size_t)((m >> 11) * 16 + (n >> 6))) * 2048 + (m & 2047)) * 64 + (n & 63);
          outH[idx] = f2h(v);
        } else {
          const size_t idx = (((size_t)((n >> 11) * 16 + (m >> 6))) * 64 + (m & 63)) * 2048 + (n & 2047);
          outH[idx] = f2h(v);
        }
      }
    }
}

__global__ __launch_bounds__(256, 2) void gemm_qk(
    const u16* __restrict__ xq, const u16* __restrict__ wqt, const float* __restrict__ bq, u16* __restrict__ qh,
    const u16* __restrict__ xk, const u16* __restrict__ wkt, const float* __restrict__ bk, u16* __restrict__ kh){
  const int z = blockIdx.z;
  const u16* A = z ? xk : xq;
  const u16* B = z ? wkt : wqt;
  const float* bias = z ? bk : bq;
  u16* out = z ? kh : qh;
  gemm_body<1>(A, B, bias, nullptr, out, 1024, 1024, blockIdx.x, blockIdx.y);
}

__global__ __launch_bounds__(256, 2) void gemm_v(
    const u16* __restrict__ wvt, const u16* __restrict__ xv, const float* __restrict__ bv, u16* __restrict__ vt){
  gemm_body<2>(wvt, xv, bv, nullptr, vt, 4096, 1024, blockIdx.x, blockIdx.y);
}

__global__ __launch_bounds__(256, 2) void gemm_fc(
    const u16* __restrict__ ctx, const u16* __restrict__ wft, const float* __restrict__ bfc, float* __restrict__ outF){
  gemm_body<0>(ctx, wft, bfc, outF, nullptr, 1024, 1024, blockIdx.x, blockIdx.y);
}

// ---------------- fused attention ----------------
// per wave: 16 q-rows of one (b,h). Swapped QK^T: mfma(K,Q) -> C[k][q],
// thread (lm,lg) holds s[k=lg*4+r][q=lm] -> dwordx4 attn stores, b64 LDS writes.
__global__ __launch_bounds__(256, 4) void attn_fused(
    const u16* __restrict__ qh_, const u16* __restrict__ kh_,
    const u16* __restrict__ vt_,
    float* __restrict__ attn_out, u16* __restrict__ ctx)
{
  constexpr int S = 2048;
  __shared__ __align__(16) u16 te[4][16][40];   // per-wave [q=16][k=32+pad], rows 80B
  const int tid = threadIdx.x, wid = tid >> 6, lane = tid & 63;
  const int lm = lane & 15, lg = lane >> 4;
  // bijective XCD swizzle: 1024 wgs, each XCD owns 4 consecutive bh entirely
  const int wg = blockIdx.x;
  const int xcd = wg & 7, li = wg >> 3;         // li 0..127
  const int bh = (xcd << 2) + (li >> 5);        // 0..31
  const int q0 = (li & 31) * 64 + wid * 16;
  const size_t base = (size_t)bh * S * 64;
  const u16* Qh = qh_ + base;
  const u16* Kh = kh_ + base;
  const u16* Vt = vt_ + base;                   // [64][S]
  float* Aout = attn_out + (size_t)bh * S * S;

  // Q B-fragments (16 q rows)
  f16x8 qb[2];
  #pragma unroll
  for (int ks = 0; ks < 2; ks++)
    qb[ks] = *(const f16x8*)(Qh + (size_t)(q0 + lm) * 64 + ks * 32 + lg * 8);

  const float SCL2 = 0.18033688011112042f;      // (1/8)*log2(e)

  // ---- pass A: denominator ----
  float part = 0.0f;
  for (int nt = 0; nt < 128; nt += 2){
    const u16* kp0 = Kh + (size_t)(nt * 16 + lm) * 64 + lg * 8;
    const u16* kp1 = kp0 + 16 * 64;
    f16x8 k00 = *(const f16x8*)(kp0);
    f16x8 k01 = *(const f16x8*)(kp0 + 32);
    f16x8 k10 = *(const f16x8*)(kp1);
    f16x8 k11 = *(const f16x8*)(kp1 + 32);
    f32x4 c0 = {}, c1 = {};
    c0 = __builtin_amdgcn_mfma_f32_16x16x32_f16(k00, qb[0], c0, 0, 0, 0);
    c0 = __builtin_amdgcn_mfma_f32_16x16x32_f16(k01, qb[1], c0, 0, 0, 0);
    c1 = __builtin_amdgcn_mfma_f32_16x16x32_f16(k10, qb[0], c1, 0, 0, 0);
    c1 = __builtin_amdgcn_mfma_f32_16x16x32_f16(k11, qb[1], c1, 0, 0, 0);
    #pragma unroll
    for (int r = 0; r < 4; r++){
      part += __builtin_amdgcn_exp2f(c0[r] * SCL2);
      part += __builtin_amdgcn_exp2f(c1[r] * SCL2);
    }
  }
  part += __shfl_xor(part, 16);
  part += __shfl_xor(part, 32);
  const float inv = 1.0f / part;                // denominator for q = q0+lm

  // ---- pass B: attn write + PV ----
  f32x4 cacc[4] = {};
  for (int nt2 = 0; nt2 < 64; nt2++){
    // issue V loads early (hide under QK^T)
    f16x8 vb[4];
    #pragma unroll
    for (int nf = 0; nf < 4; nf++)
      vb[nf] = *(const f16x8*)(Vt + (size_t)(nf * 16 + lm) * S + nt2 * 32 + lg * 8);

    const u16* kp0 = Kh + (size_t)(nt2 * 32 + lm) * 64 + lg * 8;
    const u16* kp1 = kp0 + 16 * 64;
    f16x8 k00 = *(const f16x8*)(kp0);
    f16x8 k01 = *(const f16x8*)(kp0 + 32);
    f16x8 k10 = *(const f16x8*)(kp1);
    f16x8 k11 = *(const f16x8*)(kp1 + 32);
    f32x4 c0 = {}, c1 = {};
    c0 = __builtin_amdgcn_mfma_f32_16x16x32_f16(k00, qb[0], c0, 0, 0, 0);
    c0 = __builtin_amdgcn_mfma_f32_16x16x32_f16(k01, qb[1], c0, 0, 0, 0);
    c1 = __builtin_amdgcn_mfma_f32_16x16x32_f16(k10, qb[0], c1, 0, 0, 0);
    c1 = __builtin_amdgcn_mfma_f32_16x16x32_f16(k11, qb[1], c1, 0, 0, 0);

    #pragma unroll
    for (int half = 0; half < 2; half++){
      f32x4 c = half ? c1 : c0;
      float a[4];
      #pragma unroll
      for (int r = 0; r < 4; r++)
        a[r] = __builtin_amdgcn_exp2f(c[r] * SCL2) * inv;
      f32x4 av = { a[0], a[1], a[2], a[3] };
      // attn[q0+lm][nt*16 + lg*4 .. +3], 16B vector NT store
      float* dst = Aout + (size_t)(q0 + lm) * S + (nt2 * 2 + half) * 16 + lg * 4;
      __builtin_nontemporal_store(av, (f32x4*)dst);
      u16x4 hp;
      #pragma unroll
      for (int r = 0; r < 4; r++) hp[r] = f2h(a[r]);
      *(u16x4*)&te[wid][lm][half * 16 + lg * 4] = hp;   // b64 LDS write
    }
    // exchange: A-frag P[q=lm][k=lg*8..+7]
    f16x8 pa = *(const f16x8*)&te[wid][lm][lg * 8];
    #pragma unroll
    for (int nf = 0; nf < 4; nf++)
      cacc[nf] = __builtin_amdgcn_mfma_f32_16x16x32_f16(pa, vb[nf], cacc[nf], 0, 0, 0);
  }

  // ctx[q=lg*4+r][d=nf*16+lm] per thread
  const int b = bh >> 4, h = bh & 15;
  #pragma unroll
  for (int nf = 0; nf < 4; nf++)
    #pragma unroll
    for (int r = 0; r < 4; r++){
      int srow2 = q0 + lg * 4 + r;
      int d = nf * 16 + lm;
      ctx[(size_t)(b * 2048 + srow2) * 1024 + h * 64 + d] = f2h(cacc[nf][r]);
    }
}

// ---------------- host ----------------
extern "C" void kernel_launch(void* const* d_in, const int* in_sizes, int n_in,
                              void* d_out, int out_size, void* d_ws, size_t ws_size,
                              hipStream_t stream) {
  const float* Qi  = (const float*)d_in[0];
  const float* Ki  = (const float*)d_in[1];
  const float* Vi  = (const float*)d_in[2];
  const float* Wq  = (const float*)d_in[3];
  const float* bq  = (const float*)d_in[4];
  const float* Wk  = (const float*)d_in[5];
  const float* bk  = (const float*)d_in[6];
  const float* Wv  = (const float*)d_in[7];
  const float* bv  = (const float*)d_in[8];
  const float* Wfc = (const float*)d_in[9];
  const float* bfc = (const float*)d_in[10];

  char* w = (char*)d_ws;
  const size_t P  = 8388608;    // 8 MB
  const size_t PW = 2097152;    // 2 MB
  u16* xq  = (u16*)(w + 0*P);
  u16* xk  = (u16*)(w + 1*P);
  u16* xv  = (u16*)(w + 2*P);
  u16* qh  = (u16*)(w + 3*P);
  u16* kh  = (u16*)(w + 4*P);
  u16* vt  = (u16*)(w + 5*P);
  u16* ctx = (u16*)(w + 6*P);
  char* w2 = w + 7*P;
  u16* wqt = (u16*)(w2 + 0*PW);
  u16* wkt = (u16*)(w2 + 1*PW);
  u16* wvt = (u16*)(w2 + 2*PW);
  u16* wft = (u16*)(w2 + 3*PW);

  float* outp  = (float*)d_out;
  float* attnp = outp + 4194304;          // out = 2*2048*1024

  convert_x3<<<12288, 256, 0, stream>>>(Qi, Ki, Vi, xq, xk, xv);
  transpose_w4<<<dim3(16, 16, 4), 256, 0, stream>>>(Wq, Wk, Wv, Wfc, wqt, wkt, wvt, wft);

  // q,k projections (batched), head-major f16 output
  gemm_qk<<<dim3(8, 32, 2), 256, 0, stream>>>(xq, wqt, bq, qh, xk, wkt, bk, kh);
  // v projection, transposed output v^T[b][h][d][s]
  gemm_v<<<dim3(32, 8), 256, 0, stream>>>(wvt, xv, bv, vt);
  // fused scores + softmax + attn-write + PV
  attn_fused<<<1024, 256, 0, stream>>>(qh, kh, vt, attnp, ctx);
  // output projection
  gemm_fc<<<dim3(8, 32), 256, 0, stream>>>(ctx, wft, bfc, outp);
}

// Round 4
// 452.430 us; speedup vs baseline: 1.1114x; 1.0093x over previous
//
#include <hip/hip_runtime.h>

typedef unsigned short u16;
typedef _Float16 f16;
typedef __attribute__((ext_vector_type(8))) f16 f16x8;
typedef __attribute__((ext_vector_type(4))) float f32x4;
typedef __attribute__((ext_vector_type(4))) u16 u16x4;
typedef __attribute__((ext_vector_type(8))) u16 u16x8;

__device__ __forceinline__ u16 f2h(float x){
  f16 h = (f16)x;
  return __builtin_bit_cast(u16, h);
}
__device__ __forceinline__ float h2f(u16 v){
  return (float)__builtin_bit_cast(f16, v);
}

__device__ __forceinline__ void stage16(const void* g, void* l){
  __builtin_amdgcn_global_load_lds(
      (const __attribute__((address_space(1))) unsigned*)g,
      (__attribute__((address_space(3))) unsigned*)l, 16, 0, 0);
}

// ---------------- converts ----------------
__global__ __launch_bounds__(256) void convert_x3(
    const float* __restrict__ in0, const float* __restrict__ in1, const float* __restrict__ in2,
    u16* __restrict__ o0, u16* __restrict__ o1, u16* __restrict__ o2){
  const int b = blockIdx.x >> 12;
  const int i = (blockIdx.x & 4095) * 256 + threadIdx.x;
  const float* in = (b == 0) ? in0 : (b == 1) ? in1 : in2;
  u16* out = (b == 0) ? o0 : (b == 1) ? o1 : o2;
  f32x4 v = ((const f32x4*)in)[i];
  u16x4 h;
  #pragma unroll
  for (int j = 0; j < 4; j++) h[j] = f2h(v[j]);
  ((u16x4*)out)[i] = h;
}

__global__ __launch_bounds__(256) void transpose_w4(
    const float* __restrict__ W0, const float* __restrict__ W1,
    const float* __restrict__ W2, const float* __restrict__ W3,
    u16* __restrict__ t0, u16* __restrict__ t1, u16* __restrict__ t2, u16* __restrict__ t3){
  __shared__ float tile[64][68];
  const int z = blockIdx.z;
  const float* W = (z == 0) ? W0 : (z == 1) ? W1 : (z == 2) ? W2 : W3;
  u16* wt = (z == 0) ? t0 : (z == 1) ? t1 : (z == 2) ? t2 : t3;
  const int tid = threadIdx.x;
  const int k0 = blockIdx.y * 64, n0 = blockIdx.x * 64;
  #pragma unroll
  for (int g = 0; g < 4; g++){
    int flat4 = g * 256 + tid;
    int row = flat4 >> 4, c4 = flat4 & 15;
    f32x4 v = *(const f32x4*)&W[(size_t)(k0 + row) * 1024 + n0 + c4 * 4];
    *(f32x4*)&tile[row][c4 * 4] = v;
  }
  __syncthreads();
  const int n = tid >> 2, kc = (tid & 3) * 16;
  u16x8 o0, o1;
  #pragma unroll
  for (int j = 0; j < 8; j++){
    o0[j] = f2h(tile[kc + j][n]);
    o1[j] = f2h(tile[kc + 8 + j][n]);
  }
  u16* dst = &wt[(size_t)(n0 + n) * 1024 + k0 + kc];
  *(u16x8*)dst = o0;
  *(u16x8*)(dst + 8) = o1;
}

// ---------------- GEMM body ----------------
template<int MODE>
__device__ __forceinline__ void gemm_body(
    const u16* __restrict__ A, const u16* __restrict__ B,
    const float* __restrict__ bias,
    float* __restrict__ outF, u16* __restrict__ outH,
    int N, int K, int bx, int by)
{
  __shared__ u16 sA[128 * 32];
  __shared__ u16 sB[128 * 32];
  const int tid = threadIdx.x;
  const int wid = tid >> 6, lane = tid & 63;
  const int lm = lane & 15, lg = lane >> 4;
  const int bm = by * 128, bn = bx * 128;
  const int wrow = (wid >> 1) * 64, wcol = (wid & 1) * 64;
  const int srow = tid >> 2;
  const int skc  = (tid & 3) * 8;

  f32x4 acc[4][4] = {};

  for (int kt = 0; kt < K; kt += 32){
    {
      char* dA = (char*)sA + wid * 1024;
      char* dB = (char*)sB + wid * 1024;
      stage16(A + (size_t)(bm +      srow) * K + kt + skc, dA);
      stage16(A + (size_t)(bm + 64 + srow) * K + kt + skc, dA + 4096);
      stage16(B + (size_t)(bn +      srow) * K + kt + skc, dB);
      stage16(B + (size_t)(bn + 64 + srow) * K + kt + skc, dB + 4096);
    }
    __syncthreads();
    f16x8 af[4], bf[4];
    #pragma unroll
    for (int mf = 0; mf < 4; mf++)
      af[mf] = *(const f16x8*)&sA[(wrow + mf * 16 + lm) * 32 + lg * 8];
    #pragma unroll
    for (int nf = 0; nf < 4; nf++)
      bf[nf] = *(const f16x8*)&sB[(wcol + nf * 16 + lm) * 32 + lg * 8];
    #pragma unroll
    for (int mf = 0; mf < 4; mf++)
      #pragma unroll
      for (int nf = 0; nf < 4; nf++)
        acc[mf][nf] = __builtin_amdgcn_mfma_f32_16x16x32_f16(af[mf], bf[nf], acc[mf][nf], 0, 0, 0);
    __syncthreads();
  }

  #pragma unroll
  for (int mf = 0; mf < 4; mf++)
    #pragma unroll
    for (int nf = 0; nf < 4; nf++){
      const int n  = bn + wcol + nf * 16 + lm;
      const int mb = bm + wrow + mf * 16 + lg * 4;
      #pragma unroll
      for (int r = 0; r < 4; r++){
        const int m = mb + r;
        float v = acc[mf][nf][r] + ((MODE == 2) ? bias[m] : bias[n]);
        if constexpr (MODE == 0){
          outF[(size_t)m * N + n] = v;
        } else if constexpr (MODE == 1){
          const size_t idx = (((size_t)((m >> 11) * 16 + (n >> 6))) * 2048 + (m & 2047)) * 64 + (n & 63);
          outH[idx] = f2h(v);
        } else {
          const size_t idx = (((size_t)((n >> 11) * 16 + (m >> 6))) * 64 + (m & 63)) * 2048 + (n & 2047);
          outH[idx] = f2h(v);
        }
      }
    }
}

__global__ __launch_bounds__(256, 2) void gemm_qk(
    const u16* __restrict__ xq, const u16* __restrict__ wqt, const float* __restrict__ bq, u16* __restrict__ qh,
    const u16* __restrict__ xk, const u16* __restrict__ wkt, const float* __restrict__ bk, u16* __restrict__ kh){
  const int z = blockIdx.z;
  gemm_body<1>(z ? xk : xq, z ? wkt : wqt, z ? bk : bq, nullptr, z ? kh : qh,
               1024, 1024, blockIdx.x, blockIdx.y);
}

__global__ __launch_bounds__(256, 2) void gemm_v(
    const u16* __restrict__ wvt, const u16* __restrict__ xv, const float* __restrict__ bv, u16* __restrict__ vt){
  gemm_body<2>(wvt, xv, bv, nullptr, vt, 4096, 1024, blockIdx.x, blockIdx.y);
}

__global__ __launch_bounds__(256, 2) void gemm_fc(
    const u16* __restrict__ ctx, const u16* __restrict__ wft, const float* __restrict__ bfc, float* __restrict__ outF){
  gemm_body<0>(ctx, wft, bfc, outF, nullptr, 1024, 1024, blockIdx.x, blockIdx.y);
}

// ---------------- fused attention ----------------
// One wg = 16 q-rows of one (b,h); each of the 4 waves owns a 512-col k-quarter.
// Swapped QK^T: mfma(K,Q) -> C[k][q]. Pass A: partial denominators (16 iters/wave),
// combined via LDS. Pass B (16 iters/wave): identical scores, f16 P -> LDS;
// PV partials; attn written from LDS as full-128B-line f32x4 NT stores.
// Partial ctx combined across waves via LDS at the end.
__global__ __launch_bounds__(256, 4) void attn_fused(
    const u16* __restrict__ qh_, const u16* __restrict__ kh_,
    const u16* __restrict__ vt_,
    float* __restrict__ attn_out, u16* __restrict__ ctx)
{
  constexpr int S = 2048;
  __shared__ __align__(16) u16 te[4][16][40];     // per-wave P tile [q=16][k=32+pad]
  __shared__ float sred[4][16];                   // per-wave denominator partials
  __shared__ __align__(16) float cred[4][64][20]; // per-wave ctx partials [wid][d][q+pad]
  const int tid = threadIdx.x, wid = tid >> 6, lane = tid & 63;
  const int lm = lane & 15, lg = lane >> 4;
  // bijective XCD swizzle: 4096 wgs, each XCD owns 4 consecutive bh entirely
  const int wg = blockIdx.x;
  const int xcd = wg & 7, li = wg >> 3;           // li 0..511
  const int bh = (xcd << 2) + (li >> 7);          // 0..31
  const int q0 = (li & 127) * 16;
  const size_t base = (size_t)bh * S * 64;
  const u16* Qh = qh_ + base;
  const u16* Kh = kh_ + base;
  const u16* Vt = vt_ + base;                     // [64][S]
  float* Aout = attn_out + (size_t)bh * S * S;
  const int kbase = wid * 512;                    // this wave's k-quarter

  // Q B-fragments (16 q rows, shared by all waves)
  f16x8 qb[2];
  #pragma unroll
  for (int ks = 0; ks < 2; ks++)
    qb[ks] = *(const f16x8*)(Qh + (size_t)(q0 + lm) * 64 + ks * 32 + lg * 8);

  const float SCL2 = 0.18033688011112042f;        // (1/8)*log2(e)

  // ---- pass A: partial denominator over this wave's quarter ----
  float part0 = 0.0f, part1 = 0.0f;
  for (int nt2 = 0; nt2 < 16; nt2++){
    const u16* kp0 = Kh + (size_t)(kbase + nt2 * 32 + lm) * 64 + lg * 8;
    const u16* kp1 = kp0 + 16 * 64;
    f16x8 k00 = *(const f16x8*)(kp0);
    f16x8 k01 = *(const f16x8*)(kp0 + 32);
    f16x8 k10 = *(const f16x8*)(kp1);
    f16x8 k11 = *(const f16x8*)(kp1 + 32);
    f32x4 c0 = {}, c1 = {};
    c0 = __builtin_amdgcn_mfma_f32_16x16x32_f16(k00, qb[0], c0, 0, 0, 0);
    c0 = __builtin_amdgcn_mfma_f32_16x16x32_f16(k01, qb[1], c0, 0, 0, 0);
    c1 = __builtin_amdgcn_mfma_f32_16x16x32_f16(k10, qb[0], c1, 0, 0, 0);
    c1 = __builtin_amdgcn_mfma_f32_16x16x32_f16(k11, qb[1], c1, 0, 0, 0);
    #pragma unroll
    for (int r = 0; r < 4; r++){
      part0 += __builtin_amdgcn_exp2f(c0[r] * SCL2);
      part1 += __builtin_amdgcn_exp2f(c1[r] * SCL2);
    }
  }
  float part = part0 + part1;
  part += __shfl_xor(part, 16);
  part += __shfl_xor(part, 32);
  if (lane < 16) sred[wid][lm] = part;
  __syncthreads();
  const float inv = 1.0f / (sred[0][lm] + sred[1][lm] + sred[2][lm] + sred[3][lm]);

  // ---- pass B: attn write + PV over this wave's quarter ----
  const int sq = lane >> 3;                       // store readback: q sub-row
  const int sc = (lane & 7) * 4;                  // store readback: col
  f32x4 cacc[4] = {};
  for (int nt2 = 0; nt2 < 16; nt2++){
    const int col0 = kbase + nt2 * 32;
    f16x8 vb[4];
    #pragma unroll
    for (int nf = 0; nf < 4; nf++)
      vb[nf] = *(const f16x8*)(Vt + (size_t)(nf * 16 + lm) * S + col0 + lg * 8);

    const u16* kp0 = Kh + (size_t)(col0 + lm) * 64 + lg * 8;
    const u16* kp1 = kp0 + 16 * 64;
    f16x8 k00 = *(const f16x8*)(kp0);
    f16x8 k01 = *(const f16x8*)(kp0 + 32);
    f16x8 k10 = *(const f16x8*)(kp1);
    f16x8 k11 = *(const f16x8*)(kp1 + 32);
    f32x4 c0 = {}, c1 = {};
    c0 = __builtin_amdgcn_mfma_f32_16x16x32_f16(k00, qb[0], c0, 0, 0, 0);
    c0 = __builtin_amdgcn_mfma_f32_16x16x32_f16(k01, qb[1], c0, 0, 0, 0);
    c1 = __builtin_amdgcn_mfma_f32_16x16x32_f16(k10, qb[0], c1, 0, 0, 0);
    c1 = __builtin_amdgcn_mfma_f32_16x16x32_f16(k11, qb[1], c1, 0, 0, 0);

    #pragma unroll
    for (int half = 0; half < 2; half++){
      f32x4 c = half ? c1 : c0;
      u16x4 hp;
      #pragma unroll
      for (int r = 0; r < 4; r++)
        hp[r] = f2h(__builtin_amdgcn_exp2f(c[r] * SCL2) * inv);
      *(u16x4*)&te[wid][lm][half * 16 + lg * 4] = hp;   // b64 LDS write
    }
    // PV A-frag: P[q=lm][k=lg*8..+7]
    f16x8 pa = *(const f16x8*)&te[wid][lm][lg * 8];
    #pragma unroll
    for (int nf = 0; nf < 4; nf++)
      cacc[nf] = __builtin_amdgcn_mfma_f32_16x16x32_f16(pa, vb[nf], cacc[nf], 0, 0, 0);
    // attn store: 8 lanes per q-row x 32 cols -> each instr = 8 full 128B lines
    #pragma unroll
    for (int i2 = 0; i2 < 2; i2++){
      const int q = i2 * 8 + sq;
      u16x4 hv = *(const u16x4*)&te[wid][q][sc];
      f32x4 av = { h2f(hv[0]), h2f(hv[1]), h2f(hv[2]), h2f(hv[3]) };
      __builtin_nontemporal_store(av, (f32x4*)(Aout + (size_t)(q0 + q) * S + col0 + sc));
    }
  }

  // ---- combine partial ctx across waves ----
  #pragma unroll
  for (int nf = 0; nf < 4; nf++)
    *(f32x4*)&cred[wid][nf * 16 + lm][lg * 4] = cacc[nf];
  __syncthreads();
  // 1024 (q,d) pairs; wave w handles q block w*4..w*4+3, lanes = d
  const int b = bh >> 4, h = bh & 15;
  const int rd = lane;                            // d = 0..63
  const int rq = wid * 4;
  f32x4 s0 = *(const f32x4*)&cred[0][rd][rq];
  f32x4 s1 = *(const f32x4*)&cred[1][rd][rq];
  f32x4 s2 = *(const f32x4*)&cred[2][rd][rq];
  f32x4 s3 = *(const f32x4*)&cred[3][rd][rq];
  #pragma unroll
  for (int j = 0; j < 4; j++){
    float v = s0[j] + s1[j] + s2[j] + s3[j];
    ctx[(size_t)(b * 2048 + q0 + rq + j) * 1024 + h * 64 + rd] = f2h(v);
  }
}

// ---------------- host ----------------
extern "C" void kernel_launch(void* const* d_in, const int* in_sizes, int n_in,
                              void* d_out, int out_size, void* d_ws, size_t ws_size,
                              hipStream_t stream) {
  const float* Qi  = (const float*)d_in[0];
  const float* Ki  = (const float*)d_in[1];
  const float* Vi  = (const float*)d_in[2];
  const float* Wq  = (const float*)d_in[3];
  const float* bq  = (const float*)d_in[4];
  const float* Wk  = (const float*)d_in[5];
  const float* bk  = (const float*)d_in[6];
  const float* Wv  = (const float*)d_in[7];
  const float* bv  = (const float*)d_in[8];
  const float* Wfc = (const float*)d_in[9];
  const float* bfc = (const float*)d_in[10];

  char* w = (char*)d_ws;
  const size_t P  = 8388608;    // 8 MB
  const size_t PW = 2097152;    // 2 MB
  u16* xq  = (u16*)(w + 0*P);
  u16* xk  = (u16*)(w + 1*P);
  u16* xv  = (u16*)(w + 2*P);
  u16* qh  = (u16*)(w + 3*P);
  u16* kh  = (u16*)(w + 4*P);
  u16* vt  = (u16*)(w + 5*P);
  u16* ctx = (u16*)(w + 6*P);
  char* w2 = w + 7*P;
  u16* wqt = (u16*)(w2 + 0*PW);
  u16* wkt = (u16*)(w2 + 1*PW);
  u16* wvt = (u16*)(w2 + 2*PW);
  u16* wft = (u16*)(w2 + 3*PW);

  float* outp  = (float*)d_out;
  float* attnp = outp + 4194304;          // out = 2*2048*1024

  convert_x3<<<12288, 256, 0, stream>>>(Qi, Ki, Vi, xq, xk, xv);
  transpose_w4<<<dim3(16, 16, 4), 256, 0, stream>>>(Wq, Wk, Wv, Wfc, wqt, wkt, wvt, wft);

  gemm_qk<<<dim3(8, 32, 2), 256, 0, stream>>>(xq, wqt, bq, qh, xk, wkt, bk, kh);
  gemm_v<<<dim3(32, 8), 256, 0, stream>>>(wvt, xv, bv, vt);
  attn_fused<<<4096, 256, 0, stream>>>(qh, kh, vt, attnp, ctx);
  gemm_fc<<<dim3(8, 32), 256, 0, stream>>>(ctx, wft, bfc, outp);
}

// Round 5
// 424.564 us; speedup vs baseline: 1.1844x; 1.0656x over previous
//
#include <hip/hip_runtime.h>

typedef unsigned short u16;
typedef _Float16 f16;
typedef __attribute__((ext_vector_type(8))) f16 f16x8;
typedef __attribute__((ext_vector_type(4))) float f32x4;
typedef __attribute__((ext_vector_type(4))) u16 u16x4;
typedef __attribute__((ext_vector_type(8))) u16 u16x8;

__device__ __forceinline__ u16 f2h(float x){
  f16 h = (f16)x;
  return __builtin_bit_cast(u16, h);
}
__device__ __forceinline__ float h2f(u16 v){
  return (float)__builtin_bit_cast(f16, v);
}

__device__ __forceinline__ void stage16(const void* g, void* l){
  __builtin_amdgcn_global_load_lds(
      (const __attribute__((address_space(1))) unsigned*)g,
      (__attribute__((address_space(3))) unsigned*)l, 16, 0, 0);
}

// ---------------- converts ----------------
__global__ __launch_bounds__(256) void convert_x3(
    const float* __restrict__ in0, const float* __restrict__ in1, const float* __restrict__ in2,
    u16* __restrict__ o0, u16* __restrict__ o1, u16* __restrict__ o2){
  const int b = blockIdx.x >> 12;
  const int i = (blockIdx.x & 4095) * 256 + threadIdx.x;
  const float* in = (b == 0) ? in0 : (b == 1) ? in1 : in2;
  u16* out = (b == 0) ? o0 : (b == 1) ? o1 : o2;
  f32x4 v = ((const f32x4*)in)[i];
  u16x4 h;
  #pragma unroll
  for (int j = 0; j < 4; j++) h[j] = f2h(v[j]);
  ((u16x4*)out)[i] = h;
}

__global__ __launch_bounds__(256) void transpose_w4(
    const float* __restrict__ W0, const float* __restrict__ W1,
    const float* __restrict__ W2, const float* __restrict__ W3,
    u16* __restrict__ t0, u16* __restrict__ t1, u16* __restrict__ t2, u16* __restrict__ t3){
  __shared__ float tile[64][68];
  const int z = blockIdx.z;
  const float* W = (z == 0) ? W0 : (z == 1) ? W1 : (z == 2) ? W2 : W3;
  u16* wt = (z == 0) ? t0 : (z == 1) ? t1 : (z == 2) ? t2 : t3;
  const int tid = threadIdx.x;
  const int k0 = blockIdx.y * 64, n0 = blockIdx.x * 64;
  #pragma unroll
  for (int g = 0; g < 4; g++){
    int flat4 = g * 256 + tid;
    int row = flat4 >> 4, c4 = flat4 & 15;
    f32x4 v = *(const f32x4*)&W[(size_t)(k0 + row) * 1024 + n0 + c4 * 4];
    *(f32x4*)&tile[row][c4 * 4] = v;
  }
  __syncthreads();
  const int n = tid >> 2, kc = (tid & 3) * 16;
  u16x8 o0, o1;
  #pragma unroll
  for (int j = 0; j < 8; j++){
    o0[j] = f2h(tile[kc + j][n]);
    o1[j] = f2h(tile[kc + 8 + j][n]);
  }
  u16* dst = &wt[(size_t)(n0 + n) * 1024 + k0 + kc];
  *(u16x8*)dst = o0;
  *(u16x8*)(dst + 8) = o1;
}

// ---------------- GEMM body ----------------
template<int MODE>
__device__ __forceinline__ void gemm_body(
    const u16* __restrict__ A, const u16* __restrict__ B,
    const float* __restrict__ bias,
    float* __restrict__ outF, u16* __restrict__ outH,
    int N, int K, int bx, int by)
{
  __shared__ u16 sA[128 * 32];
  __shared__ u16 sB[128 * 32];
  const int tid = threadIdx.x;
  const int wid = tid >> 6, lane = tid & 63;
  const int lm = lane & 15, lg = lane >> 4;
  const int bm = by * 128, bn = bx * 128;
  const int wrow = (wid >> 1) * 64, wcol = (wid & 1) * 64;
  const int srow = tid >> 2;
  const int skc  = (tid & 3) * 8;

  f32x4 acc[4][4] = {};

  for (int kt = 0; kt < K; kt += 32){
    {
      char* dA = (char*)sA + wid * 1024;
      char* dB = (char*)sB + wid * 1024;
      stage16(A + (size_t)(bm +      srow) * K + kt + skc, dA);
      stage16(A + (size_t)(bm + 64 + srow) * K + kt + skc, dA + 4096);
      stage16(B + (size_t)(bn +      srow) * K + kt + skc, dB);
      stage16(B + (size_t)(bn + 64 + srow) * K + kt + skc, dB + 4096);
    }
    __syncthreads();
    f16x8 af[4], bf[4];
    #pragma unroll
    for (int mf = 0; mf < 4; mf++)
      af[mf] = *(const f16x8*)&sA[(wrow + mf * 16 + lm) * 32 + lg * 8];
    #pragma unroll
    for (int nf = 0; nf < 4; nf++)
      bf[nf] = *(const f16x8*)&sB[(wcol + nf * 16 + lm) * 32 + lg * 8];
    #pragma unroll
    for (int mf = 0; mf < 4; mf++)
      #pragma unroll
      for (int nf = 0; nf < 4; nf++)
        acc[mf][nf] = __builtin_amdgcn_mfma_f32_16x16x32_f16(af[mf], bf[nf], acc[mf][nf], 0, 0, 0);
    __syncthreads();
  }

  #pragma unroll
  for (int mf = 0; mf < 4; mf++)
    #pragma unroll
    for (int nf = 0; nf < 4; nf++){
      const int n  = bn + wcol + nf * 16 + lm;
      const int mb = bm + wrow + mf * 16 + lg * 4;
      #pragma unroll
      for (int r = 0; r < 4; r++){
        const int m = mb + r;
        float v = acc[mf][nf][r] + ((MODE == 2) ? bias[m] : bias[n]);
        if constexpr (MODE == 0){
          outF[(size_t)m * N + n] = v;
        } else if constexpr (MODE == 1){
          const size_t idx = (((size_t)((m >> 11) * 16 + (n >> 6))) * 2048 + (m & 2047)) * 64 + (n & 63);
          outH[idx] = f2h(v);
        } else {
          const size_t idx = (((size_t)((n >> 11) * 16 + (m >> 6))) * 64 + (m & 63)) * 2048 + (n & 2047);
          outH[idx] = f2h(v);
        }
      }
    }
}

__global__ __launch_bounds__(256, 2) void gemm_qk(
    const u16* __restrict__ xq, const u16* __restrict__ wqt, const float* __restrict__ bq, u16* __restrict__ qh,
    const u16* __restrict__ xk, const u16* __restrict__ wkt, const float* __restrict__ bk, u16* __restrict__ kh){
  const int z = blockIdx.z;
  gemm_body<1>(z ? xk : xq, z ? wkt : wqt, z ? bk : bq, nullptr, z ? kh : qh,
               1024, 1024, blockIdx.x, blockIdx.y);
}

__global__ __launch_bounds__(256, 2) void gemm_v(
    const u16* __restrict__ wvt, const u16* __restrict__ xv, const float* __restrict__ bv, u16* __restrict__ vt){
  gemm_body<2>(wvt, xv, bv, nullptr, vt, 4096, 1024, blockIdx.x, blockIdx.y);
}

__global__ __launch_bounds__(256, 2) void gemm_fc(
    const u16* __restrict__ ctx, const u16* __restrict__ wft, const float* __restrict__ bfc, float* __restrict__ outF){
  gemm_body<0>(ctx, wft, bfc, outF, nullptr, 1024, 1024, blockIdx.x, blockIdx.y);
}

// ---------------- fused attention (single pass + burst store) ----------------
// One wg = 16 q-rows of one (b,h); each of 4 waves owns a 512-col k-quarter.
// K-loop: QK^T (swapped), e=exp2(s*c) unnormalized -> f16 LDS quarter buffer;
// denominator accumulated in f32 same pass; PV on unnormalized P, rescaled after.
// Store phase: rows written as 2KB-contiguous wave bursts (sequential stream).
__global__ __launch_bounds__(256, 2) void attn_fused(
    const u16* __restrict__ qh_, const u16* __restrict__ kh_,
    const u16* __restrict__ vt_,
    float* __restrict__ attn_out, u16* __restrict__ ctx)
{
  constexpr int S = 2048;
  __shared__ __align__(16) char smem[4 * 16 * 520 * 2];  // 66560 B: per-wave [16][520] u16
  __shared__ float sred[4][16];
  __shared__ float linv[16];
  const int tid = threadIdx.x, wid = tid >> 6, lane = tid & 63;
  const int lm = lane & 15, lg = lane >> 4;
  u16 (*pb)[520] = (u16 (*)[520])(smem + wid * (16 * 520 * 2));
  // bijective XCD swizzle: 4096 wgs, each XCD owns 4 consecutive bh entirely
  const int wg = blockIdx.x;
  const int xcd = wg & 7, li = wg >> 3;           // li 0..511
  const int bh = (xcd << 2) + (li >> 7);          // 0..31
  const int q0 = (li & 127) * 16;
  const size_t base = (size_t)bh * S * 64;
  const u16* Qh = qh_ + base;
  const u16* Kh = kh_ + base;
  const u16* Vt = vt_ + base;                     // [64][S]
  float* Aout = attn_out + (size_t)bh * S * S;
  const int kbase = wid * 512;                    // this wave's k-quarter

  // Q B-fragments (16 q rows, shared by all waves)
  f16x8 qb[2];
  #pragma unroll
  for (int ks = 0; ks < 2; ks++)
    qb[ks] = *(const f16x8*)(Qh + (size_t)(q0 + lm) * 64 + ks * 32 + lg * 8);

  const float SCL2 = 0.18033688011112042f;        // (1/8)*log2(e)

  // ---- single pass: scores -> unnormalized exp in LDS, denom + PV partials ----
  float part = 0.0f;
  f32x4 cacc[4] = {};
  for (int nt2 = 0; nt2 < 16; nt2++){
    const int col0 = kbase + nt2 * 32;
    f16x8 vb[4];
    #pragma unroll
    for (int nf = 0; nf < 4; nf++)
      vb[nf] = *(const f16x8*)(Vt + (size_t)(nf * 16 + lm) * S + col0 + lg * 8);

    const u16* kp0 = Kh + (size_t)(col0 + lm) * 64 + lg * 8;
    const u16* kp1 = kp0 + 16 * 64;
    f16x8 k00 = *(const f16x8*)(kp0);
    f16x8 k01 = *(const f16x8*)(kp0 + 32);
    f16x8 k10 = *(const f16x8*)(kp1);
    f16x8 k11 = *(const f16x8*)(kp1 + 32);
    f32x4 c0 = {}, c1 = {};
    c0 = __builtin_amdgcn_mfma_f32_16x16x32_f16(k00, qb[0], c0, 0, 0, 0);
    c0 = __builtin_amdgcn_mfma_f32_16x16x32_f16(k01, qb[1], c0, 0, 0, 0);
    c1 = __builtin_amdgcn_mfma_f32_16x16x32_f16(k10, qb[0], c1, 0, 0, 0);
    c1 = __builtin_amdgcn_mfma_f32_16x16x32_f16(k11, qb[1], c1, 0, 0, 0);

    #pragma unroll
    for (int half = 0; half < 2; half++){
      f32x4 c = half ? c1 : c0;
      u16x4 hp;
      #pragma unroll
      for (int r = 0; r < 4; r++){
        float e = __builtin_amdgcn_exp2f(c[r] * SCL2);
        part += e;
        hp[r] = f2h(e);
      }
      *(u16x4*)&pb[lm][nt2 * 32 + half * 16 + lg * 4] = hp;
    }
    // PV on unnormalized P: A-frag P[q=lm][k-slot lg*8..+7]
    f16x8 pa = *(const f16x8*)&pb[lm][nt2 * 32 + lg * 8];
    #pragma unroll
    for (int nf = 0; nf < 4; nf++)
      cacc[nf] = __builtin_amdgcn_mfma_f32_16x16x32_f16(pa, vb[nf], cacc[nf], 0, 0, 0);
  }

  // ---- denominator combine ----
  part += __shfl_xor(part, 16);
  part += __shfl_xor(part, 32);
  if (lane < 16) sred[wid][lm] = part;
  __syncthreads();
  if (tid < 16) linv[tid] = 1.0f / (sred[0][tid] + sred[1][tid] + sred[2][tid] + sred[3][tid]);
  __syncthreads();

  // ---- burst store phase: 16 rows x 2KB contiguous per wave-instruction ----
  #pragma unroll 4
  for (int r = 0; r < 16; r++){
    u16x8 hv = *(const u16x8*)&pb[r][lane * 8];
    const float iv = linv[r];
    f32x4 lo = { h2f(hv[0]) * iv, h2f(hv[1]) * iv, h2f(hv[2]) * iv, h2f(hv[3]) * iv };
    f32x4 hi = { h2f(hv[4]) * iv, h2f(hv[5]) * iv, h2f(hv[6]) * iv, h2f(hv[7]) * iv };
    float* dst = Aout + (size_t)(q0 + r) * S + kbase + lane * 8;
    *(f32x4*)dst = lo;
    *(f32x4*)(dst + 4) = hi;
  }

  // ---- rescale PV partials, combine across waves ----
  const float myinv = linv[lg * 4 + 0];           // note: per-element below
  (void)myinv;
  float iv4[4];
  #pragma unroll
  for (int r = 0; r < 4; r++) iv4[r] = linv[lg * 4 + r];

  __syncthreads();                                // all pb reads done; overlay cred
  float (*cred)[64][20] = (float (*)[64][20])smem;  // [4][64][20] = 20480 B
  #pragma unroll
  for (int nf = 0; nf < 4; nf++){
    f32x4 sc;
    #pragma unroll
    for (int r = 0; r < 4; r++) sc[r] = cacc[nf][r] * iv4[r];
    *(f32x4*)&cred[wid][nf * 16 + lm][lg * 4] = sc;
  }
  __syncthreads();
  const int b = bh >> 4, h = bh & 15;
  const int rd = lane;                            // d = 0..63
  const int rq = wid * 4;
  f32x4 s0 = *(const f32x4*)&cred[0][rd][rq];
  f32x4 s1 = *(const f32x4*)&cred[1][rd][rq];
  f32x4 s2 = *(const f32x4*)&cred[2][rd][rq];
  f32x4 s3 = *(const f32x4*)&cred[3][rd][rq];
  #pragma unroll
  for (int j = 0; j < 4; j++){
    float v = s0[j] + s1[j] + s2[j] + s3[j];
    ctx[(size_t)(b * 2048 + q0 + rq + j) * 1024 + h * 64 + rd] = f2h(v);
  }
}

// ---------------- host ----------------
extern "C" void kernel_launch(void* const* d_in, const int* in_sizes, int n_in,
                              void* d_out, int out_size, void* d_ws, size_t ws_size,
                              hipStream_t stream) {
  const float* Qi  = (const float*)d_in[0];
  const float* Ki  = (const float*)d_in[1];
  const float* Vi  = (const float*)d_in[2];
  const float* Wq  = (const float*)d_in[3];
  const float* bq  = (const float*)d_in[4];
  const float* Wk  = (const float*)d_in[5];
  const float* bk  = (const float*)d_in[6];
  const float* Wv  = (const float*)d_in[7];
  const float* bv  = (const float*)d_in[8];
  const float* Wfc = (const float*)d_in[9];
  const float* bfc = (const float*)d_in[10];

  char* w = (char*)d_ws;
  const size_t P  = 8388608;    // 8 MB
  const size_t PW = 2097152;    // 2 MB
  u16* xq  = (u16*)(w + 0*P);
  u16* xk  = (u16*)(w + 1*P);
  u16* xv  = (u16*)(w + 2*P);
  u16* qh  = (u16*)(w + 3*P);
  u16* kh  = (u16*)(w + 4*P);
  u16* vt  = (u16*)(w + 5*P);
  u16* ctx = (u16*)(w + 6*P);
  char* w2 = w + 7*P;
  u16* wqt = (u16*)(w2 + 0*PW);
  u16* wkt = (u16*)(w2 + 1*PW);
  u16* wvt = (u16*)(w2 + 2*PW);
  u16* wft = (u16*)(w2 + 3*PW);

  float* outp  = (float*)d_out;
  float* attnp = outp + 4194304;          // out = 2*2048*1024

  convert_x3<<<12288, 256, 0, stream>>>(Qi, Ki, Vi, xq, xk, xv);
  transpose_w4<<<dim3(16, 16, 4), 256, 0, stream>>>(Wq, Wk, Wv, Wfc, wqt, wkt, wvt, wft);

  gemm_qk<<<dim3(8, 32, 2), 256, 0, stream>>>(xq, wqt, bq, qh, xk, wkt, bk, kh);
  gemm_v<<<dim3(32, 8), 256, 0, stream>>>(wvt, xv, bv, vt);
  attn_fused<<<4096, 256, 0, stream>>>(qh, kh, vt, attnp, ctx);
  gemm_fc<<<dim3(8, 32), 256, 0, stream>>>(ctx, wft, bfc, outp);
}